// Round 2
// baseline (876.814 us; speedup 1.0000x reference)
//
#include <hip/hip_runtime.h>
#include <hip/hip_bf16.h>
#include <stdint.h>

#define B_ 16
#define N_ 64
#define S_ 4096
#define C_ 384
#define H_ 6
#define DH_ 64
#define SCALE_ 0.125f
#define TAU_ 2e-4f
#define LISTCAP 262144

typedef __attribute__((ext_vector_type(8))) short bf16x8;
typedef __attribute__((ext_vector_type(4))) float f32x4;

static __device__ __forceinline__ unsigned short f2bf(float x) {
    union { float f; unsigned u; } v; v.f = x;
    unsigned r = v.u + 0x7FFFu + ((v.u >> 16) & 1u);
    return (unsigned short)(r >> 16);
}
static __device__ __forceinline__ float bf2f(unsigned short b) {
    union { unsigned u; float f; } v; v.u = ((unsigned)b) << 16; return v.f;
}
static __device__ __forceinline__ float bfu_lo(unsigned u) {
    union { unsigned u; float f; } v; v.u = u << 16; return v.f;
}
static __device__ __forceinline__ float bfu_hi(unsigned u) {
    union { unsigned u; float f; } v; v.u = u & 0xFFFF0000u; return v.f;
}

// async global->LDS, 16B/lane; LDS dest = wave-uniform base + lane*16
static __device__ __forceinline__ void gl_lds16(const void* g, void* l) {
    __builtin_amdgcn_global_load_lds(
        (const __attribute__((address_space(1))) unsigned int*)g,
        (__attribute__((address_space(3))) unsigned int*)l, 16, 0, 0);
}

// ---------------------------------------------------------------------------
// K0: prep — key -> khi/klo (bf16 hi + bf16 residual)
// ---------------------------------------------------------------------------
__global__ __launch_bounds__(256) void prep_kernel(const float* __restrict__ key,
                                                   unsigned short* __restrict__ khi,
                                                   unsigned short* __restrict__ klo) {
    size_t gid = (size_t)blockIdx.x * 256 + threadIdx.x;
    size_t base = gid * 8;
    float4 x0 = *(const float4*)(key + base);
    float4 x1 = *(const float4*)(key + base + 4);
    float xs[8] = { x0.x, x0.y, x0.z, x0.w, x1.x, x1.y, x1.z, x1.w };
    unsigned short hi[8], lo[8];
#pragma unroll
    for (int i = 0; i < 8; ++i) {
        hi[i] = f2bf(xs[i]);
        lo[i] = f2bf(xs[i] - bf2f(hi[i]));
    }
    *(bf16x8*)(khi + base) = *(bf16x8*)hi;
    *(bf16x8*)(klo + base) = *(bf16x8*)lo;
}

// ---------------------------------------------------------------------------
// K1: fused q-proj + qk (fp32 exact) + bf16 hi/lo split. 4 rows/block.
// ---------------------------------------------------------------------------
__global__ __launch_bounds__(384) void qk_fused_kernel(const float* __restrict__ query,
                                                       const float* __restrict__ Wq,
                                                       const float* __restrict__ Wk,
                                                       float* __restrict__ qk,
                                                       unsigned short* __restrict__ qkhi,
                                                       unsigned short* __restrict__ qklo) {
    __shared__ float qstage[4][C_];
    __shared__ float qrow[4][C_];
    int ng = blockIdx.x, b = blockIdx.y;
    int t = threadIdx.x;
    int n0 = ng * 4;
#pragma unroll
    for (int i = 0; i < 4; ++i)
        qstage[i][t] = query[((size_t)(b * N_ + n0 + i)) * C_ + t];
    __syncthreads();
    {
        float a[4];
#pragma unroll
        for (int i = 0; i < 4; ++i) a[i] = 0.f;
        const float4* wq = (const float4*)(Wq + (size_t)t * C_);
        for (int c4 = 0; c4 < C_ / 4; ++c4) {
            float4 w = wq[c4];
#pragma unroll
            for (int i = 0; i < 4; ++i)
                a[i] += qstage[i][c4 * 4 + 0] * w.x + qstage[i][c4 * 4 + 1] * w.y
                      + qstage[i][c4 * 4 + 2] * w.z + qstage[i][c4 * 4 + 3] * w.w;
        }
#pragma unroll
        for (int i = 0; i < 4; ++i) qrow[i][t] = a[i] * SCALE_;
    }
    __syncthreads();
    for (int h = 0; h < H_; ++h) {
        float a[4];
#pragma unroll
        for (int i = 0; i < 4; ++i) a[i] = 0.f;
        const float* wk = Wk + (size_t)h * DH_ * C_ + t;
#pragma unroll 4
        for (int d = 0; d < DH_; ++d) {
            float w = wk[(size_t)d * C_];
#pragma unroll
            for (int i = 0; i < 4; ++i) a[i] += qrow[i][h * DH_ + d] * w;
        }
#pragma unroll
        for (int i = 0; i < 4; ++i) {
            size_t o = ((size_t)(b * H_ + h) * N_ + n0 + i) * C_ + t;
            float v = a[i];
            qk[o] = v;
            unsigned short hi = f2bf(v);
            qkhi[o] = hi;
            qklo[o] = f2bf(v - bf2f(hi));
        }
    }
}

// ---------------------------------------------------------------------------
// K2: logits via 3-pass bf16 MFMA + argmax. 64n x 256 tokens.
// ROUND-THIS: revert dbuf (r1 regression: VGPR 148 > 128 cliff + 80KB LDS
// -> 2 blocks/CU, occupancy 22->11%). Instead: same single-buffer 40KB
// structure re-partitioned to 8 WAVES (512 thr). Per wave: 32q x 64tok ->
// acc[2][4] = 32 VGPR (was 64). __launch_bounds__(512,6) caps VGPR at 85
// -> 6 waves/SIMD = 24 waves/CU (3 blocks x 40KB = 120KB LDS), +50% TLP
// over round-0's 16 waves/CU, with half-size per-barrier MFMA/ds phases
// for finer cross-wave interleave. Worst case (cap missed -> 2 blocks x 8
// waves) == round-0 occupancy. LDS layout/swizzle/epilogue logic unchanged.
// ---------------------------------------------------------------------------
__global__ __launch_bounds__(512, 6) void attn_kernel(const unsigned short* __restrict__ qkhi,
                                                      const unsigned short* __restrict__ qklo,
                                                      const unsigned short* __restrict__ khi,
                                                      const unsigned short* __restrict__ klo,
                                                      unsigned int* __restrict__ idx,
                                                      unsigned int* __restrict__ flag_cnt,
                                                      unsigned int* __restrict__ flag_list) {
    __shared__ __align__(16) unsigned short sAhi[64 * 32];
    __shared__ __align__(16) unsigned short sAlo[64 * 32];
    __shared__ __align__(16) unsigned short sBhi[256 * 32];
    __shared__ __align__(16) unsigned short sBlo[256 * 32];
    int tid = threadIdx.x;
    int w = tid >> 6, l = tid & 63;          // w in 0..7
    int wm = w >> 2, wn = w & 3;             // 2 x 4 wave grid
    int q4 = l >> 4, lm = l & 15;
    int s0 = blockIdx.x * 256;
    int h = blockIdx.y, b = blockIdx.z;
    size_t kbK = ((size_t)b * S_ + s0) * C_;
    size_t kbA = (size_t)(b * H_ + h) * N_ * C_;
    int trow16 = l >> 2;
    int tquart = ((l & 3) ^ ((l >> 3) & 3)) * 8;
    int sw = (q4 ^ ((lm >> 1) & 3)) * 8;

    f32x4 acc[2][4];
#pragma unroll
    for (int tm = 0; tm < 2; ++tm)
#pragma unroll
        for (int nt = 0; nt < 4; ++nt) acc[tm][nt] = (f32x4)0.f;

    for (int kc = 0; kc < C_; kc += 32) {
        __syncthreads();
#pragma unroll
        for (int i = 0; i < 5; ++i) {
            int gid = w * 5 + i;
            if (gid < 16) {
                gl_lds16(khi + kbK + (size_t)(gid * 16 + trow16) * C_ + kc + tquart,
                         (char*)sBhi + gid * 1024);
            } else if (gid < 32) {
                int g2 = gid - 16;
                gl_lds16(klo + kbK + (size_t)(g2 * 16 + trow16) * C_ + kc + tquart,
                         (char*)sBlo + g2 * 1024);
            } else if (gid < 36) {
                int g2 = gid - 32;
                gl_lds16(qkhi + kbA + (size_t)(g2 * 16 + trow16) * C_ + kc + tquart,
                         (char*)sAhi + g2 * 1024);
            } else {
                int g2 = gid - 36;
                gl_lds16(qklo + kbA + (size_t)(g2 * 16 + trow16) * C_ + kc + tquart,
                         (char*)sAlo + g2 * 1024);
            }
        }
        __syncthreads();
        bf16x8 ah[2], al[2];
#pragma unroll
        for (int tm = 0; tm < 2; ++tm) {
            int ar = (wm * 32 + tm * 16 + lm) * 32 + sw;
            ah[tm] = *(const bf16x8*)&sAhi[ar];
            al[tm] = *(const bf16x8*)&sAlo[ar];
        }
#pragma unroll
        for (int nt = 0; nt < 4; ++nt) {
            int nr = ((wn * 4 + nt) * 16 + lm) * 32 + sw;
            bf16x8 bh = *(const bf16x8*)&sBhi[nr];
            bf16x8 bl = *(const bf16x8*)&sBlo[nr];
#pragma unroll
            for (int tm = 0; tm < 2; ++tm) {
                acc[tm][nt] = __builtin_amdgcn_mfma_f32_16x16x32_bf16(ah[tm], bh, acc[tm][nt], 0, 0, 0);
                acc[tm][nt] = __builtin_amdgcn_mfma_f32_16x16x32_bf16(ah[tm], bl, acc[tm][nt], 0, 0, 0);
                acc[tm][nt] = __builtin_amdgcn_mfma_f32_16x16x32_bf16(al[tm], bh, acc[tm][nt], 0, 0, 0);
            }
        }
    }
    __syncthreads();

    float* rm1 = (float*)sBhi;   // scratch aliases sBhi; safe after final barrier
    float* rm2 = rm1 + 512;
    int* ri1 = (int*)(rm2 + 512);
    int* ri2 = ri1 + 512;

#pragma unroll
    for (int nt = 0; nt < 4; ++nt) {
        float m1 = -3.4e38f, m2 = -3.4e38f; int i1 = 0, i2 = 0;
#pragma unroll
        for (int tm = 0; tm < 2; ++tm)
#pragma unroll
            for (int r = 0; r < 4; ++r) {
                float v = acc[tm][nt][r];
                int row = wm * 32 + tm * 16 + q4 * 4 + r;
                if (v > m1) { m2 = m1; i2 = i1; m1 = v; i1 = row; }
                else if (v > m2) { m2 = v; i2 = row; }
            }
#pragma unroll
        for (int off = 16; off < 64; off <<= 1) {
            float om1 = __shfl_xor(m1, off), om2 = __shfl_xor(m2, off);
            int oi1 = __shfl_xor(i1, off), oi2 = __shfl_xor(i2, off);
            bool take = (om1 > m1) || (om1 == m1 && oi1 < i1);
            float w1 = take ? om1 : m1; int wi1 = take ? oi1 : i1;
            float l1 = take ? m1 : om1; int li1 = take ? i1 : oi1;
            float s2 = m2; int si2 = i2;
            if (om2 > s2) { s2 = om2; si2 = oi2; }
            if (l1 > s2) { s2 = l1; si2 = li1; }
            m1 = w1; i1 = wi1; m2 = s2; i2 = si2;
        }
        if (q4 == 0) {
            int cw = (wn * 4 + nt) * 16 + lm;      // token col 0..255
            rm1[wm * 256 + cw] = m1; rm2[wm * 256 + cw] = m2;
            ri1[wm * 256 + cw] = i1; ri2[wm * 256 + cw] = i2;
        }
    }
    __syncthreads();
    if (tid < 256) {
        float a1 = rm1[tid], a2 = rm2[tid];
        int ai1 = ri1[tid], ai2 = ri2[tid];
        float b1 = rm1[256 + tid], b2 = rm2[256 + tid];
        int bi1 = ri1[256 + tid], bi2 = ri2[256 + tid];
        float w1, s2; int wi1, wi2;
        if (b1 > a1) { w1 = b1; wi1 = bi1; s2 = a1; wi2 = ai1; if (b2 > s2) { s2 = b2; wi2 = bi2; } }
        else         { w1 = a1; wi1 = ai1; s2 = a2; wi2 = ai2; if (b1 > s2) { s2 = b1; wi2 = bi1; } }
        idx[(size_t)(b * H_ + h) * S_ + s0 + tid] = (unsigned)wi1;
        if (w1 - s2 < TAU_) {
            unsigned p = atomicAdd(flag_cnt, 1u);
            if (p < LISTCAP) {
                unsigned tok = (unsigned)((b * H_ + h) * S_ + s0 + tid);
                flag_list[p] = tok | ((unsigned)wi1 << 19) | ((unsigned)wi2 << 25);
            }
        }
    }
}

// ---------------------------------------------------------------------------
// K3: fixup — exact fp32 recompute of two candidate rows for near-ties
// ---------------------------------------------------------------------------
__global__ __launch_bounds__(256) void fixup_kernel(const float* __restrict__ qk,
                                                    const float* __restrict__ key,
                                                    const unsigned int* __restrict__ flag_list,
                                                    const unsigned int* __restrict__ flag_cnt,
                                                    unsigned int* __restrict__ idx) {
    int w = threadIdx.x >> 6, l = threadIdx.x & 63;
    unsigned total = flag_cnt[0];
    if (total > LISTCAP) total = LISTCAP;
    for (unsigned t = blockIdx.x * 4 + w; t < total; t += gridDim.x * 4) {
        unsigned e = flag_list[t];
        unsigned tok = e & 0x7FFFFu;
        int i1 = (int)((e >> 19) & 63u), i2 = (int)((e >> 25) & 63u);
        unsigned bh = tok >> 12;
        unsigned s = tok & 4095u;
        unsigned bb = bh / H_;
        int l32 = l & 31;
        const float* qrow = qk + ((size_t)bh * N_ + (l < 32 ? i1 : i2)) * C_ + l32 * 12;
        const float* krow = key + ((size_t)bb * S_ + s) * C_ + l32 * 12;
        float sum = 0.f;
#pragma unroll
        for (int c = 0; c < 12; ++c) sum += qrow[c] * krow[c];
#pragma unroll
        for (int off = 1; off < 32; off <<= 1) sum += __shfl_xor(sum, off);
        float d1 = __shfl(sum, 0);
        float d2 = __shfl(sum, 32);
        int win = (d2 > d1 || (d2 == d1 && i2 < i1)) ? i2 : i1;
        if (l == 0) idx[(size_t)bh * S_ + s] = (unsigned)win;
    }
}

// ---------------------------------------------------------------------------
// K4: hist_build — per (b,h): histogram -> scan -> counting-sort placement
// ---------------------------------------------------------------------------
__global__ __launch_bounds__(256) void hist_build_kernel(const unsigned int* __restrict__ idx,
                                                         unsigned int* __restrict__ offs,
                                                         unsigned int* __restrict__ order) {
    __shared__ unsigned int cnts[N_];
    __shared__ unsigned int pos[N_];
    int tid = threadIdx.x;
    int bh = blockIdx.x;
    if (tid < N_) cnts[tid] = 0u;
    __syncthreads();
    const unsigned int* idxp = idx + (size_t)bh * S_;
    for (int s = tid; s < S_; s += 256) atomicAdd(&cnts[idxp[s]], 1u);
    __syncthreads();
    if (tid < N_) {
        unsigned v = cnts[tid];
        unsigned x = v;
#pragma unroll
        for (int off = 1; off < 64; off <<= 1) {
            unsigned y = __shfl_up(x, off);
            if (tid >= off) x += y;
        }
        unsigned excl = x - v;
        pos[tid] = excl;
        offs[(size_t)bh * 65 + tid] = excl;
        if (tid == 63) offs[(size_t)bh * 65 + 64] = x;   // == S_
    }
    __syncthreads();
    unsigned int* op = order + (size_t)bh * S_;
    for (int s = tid; s < S_; s += 256) {
        unsigned g = idxp[s];
        unsigned p = atomicAdd(&pos[g], 1u);
        op[p] = (unsigned)s;
    }
}

// ---------------------------------------------------------------------------
// K5: agg2 — per (group, half): contiguous token list -> register accumulation
// ---------------------------------------------------------------------------
__global__ __launch_bounds__(256) void agg2_kernel(const unsigned short* __restrict__ khi,
                                                   const unsigned int* __restrict__ order,
                                                   const unsigned int* __restrict__ offs,
                                                   float* __restrict__ gpart) {
    int tid = threadIdx.x;
    int w = tid >> 6, l = tid & 63;
    int h = blockIdx.y, b = blockIdx.z;
    int bh = b * H_ + h;
    int wid = blockIdx.x * 4 + w;       // 0..127
    int g = wid >> 1, part = wid & 1;
    unsigned beg = offs[(size_t)bh * 65 + g];
    unsigned end = offs[(size_t)bh * 65 + g + 1];
    int cnt = (int)(end - beg);
    float inv = 1.f / ((float)cnt + 1.f);
    const unsigned int* op = order + (size_t)bh * S_ + beg;
    const unsigned int* kbase = (const unsigned int*)(khi + (size_t)b * S_ * C_);
    float a0 = 0.f, a1 = 0.f, a2 = 0.f, a3 = 0.f, a4 = 0.f, a5 = 0.f;
    for (int base = part * 64; base < cnt; base += 128) {
        int m = cnt - base; if (m > 64) m = 64;
        unsigned sv = (l < m) ? op[base + l] : 0u;
        for (int i = 0; i < m; ++i) {
            int s = (int)__shfl((int)sv, i);
            const unsigned int* kp = kbase + (size_t)s * (C_ / 2) + l * 3;
            unsigned u0 = kp[0], u1 = kp[1], u2 = kp[2];
            a0 += bfu_lo(u0); a1 += bfu_hi(u0);
            a2 += bfu_lo(u1); a3 += bfu_hi(u1);
            a4 += bfu_lo(u2); a5 += bfu_hi(u2);
        }
    }
    float* gp = gpart + (((size_t)bh * 2 + part) * N_ + g) * C_ + l * 6;
    float2 o0 = { a0 * inv, a1 * inv };
    float2 o1 = { a2 * inv, a3 * inv };
    float2 o2 = { a4 * inv, a5 * inv };
    ((float2*)gp)[0] = o0; ((float2*)gp)[1] = o1; ((float2*)gp)[2] = o2;
}

// ---------------------------------------------------------------------------
// K6: gv — ONE WAVE PER (bh, group): 6144 independent waves (24/CU), no
// serialized group loop. Lane d: dot(row, Wv[h*64+d]); LDS row reads are
// same-address broadcast (free); Wv is L2-resident.
// ---------------------------------------------------------------------------
__global__ __launch_bounds__(256) void gv_kernel(const float* __restrict__ gpart,
                                                 const float* __restrict__ Wv,
                                                 float* __restrict__ gvn) {
    __shared__ float rows[4][C_];
    int tid = threadIdx.x;
    int w = tid >> 6, l = tid & 63;
    int h = blockIdx.y, b = blockIdx.z;
    int bh = b * H_ + h;
    int g = blockIdx.x * 4 + w;
    const float* s0 = gpart + (((size_t)bh * 2 + 0) * N_ + g) * C_;
    const float* s1 = gpart + (((size_t)bh * 2 + 1) * N_ + g) * C_;
    for (int i = l; i < C_ / 4; i += 64) {
        float4 x = ((const float4*)s0)[i];
        float4 y = ((const float4*)s1)[i];
        float4 z = { x.x + y.x, x.y + y.y, x.z + y.z, x.w + y.w };
        *(float4*)&rows[w][i * 4] = z;
    }
    __syncthreads();   // one barrier; waves independent afterwards
    const float* wrow = Wv + (size_t)(h * DH_ + l) * C_;
    float acc = 0.f;
#pragma unroll 8
    for (int c4 = 0; c4 < C_ / 4; ++c4) {
        float4 a = *(const float4*)&rows[w][c4 * 4];
        float4 wv = *(const float4*)&wrow[c4 * 4];
        acc += a.x * wv.x + a.y * wv.y + a.z * wv.z + a.w * wv.w;
    }
    gvn[((size_t)bh * N_ + g) * DH_ + l] = acc;
}

// ---------------------------------------------------------------------------
// K7: out[b,n,j] = sum_{h,d} gvn[b,h,n,d] * Wp[j, h*64+d] + bp[j]
// ---------------------------------------------------------------------------
__global__ __launch_bounds__(384) void out_kernel(const float* __restrict__ gvn,
                                                  const float* __restrict__ Wp,
                                                  const float* __restrict__ bp,
                                                  float* __restrict__ out) {
    __shared__ float vals[C_];
    int bn = blockIdx.x;
    int b = bn >> 6, n = bn & 63;
    int t = threadIdx.x;
    int h = t >> 6, d = t & 63;
    vals[t] = gvn[((size_t)(b * H_ + h) * N_ + n) * DH_ + d];
    __syncthreads();
    const float4* w4 = (const float4*)(Wp + (size_t)t * C_);
    const float4* v4 = (const float4*)vals;
    float s = bp[t];
#pragma unroll 8
    for (int i = 0; i < C_ / 4; ++i) {
        float4 a = v4[i]; float4 w = w4[i];
        s += a.x * w.x + a.y * w.y + a.z * w.z + a.w * w.w;
    }
    out[(size_t)bn * C_ + t] = s;
}

// ---------------------------------------------------------------------------
extern "C" void kernel_launch(void* const* d_in, const int* in_sizes, int n_in,
                              void* d_out, int out_size, void* d_ws, size_t ws_size,
                              hipStream_t stream) {
    (void)in_sizes; (void)n_in; (void)out_size; (void)ws_size;
    const float* query = (const float*)d_in[0];
    const float* key   = (const float*)d_in[1];
    const float* Wq    = (const float*)d_in[2];
    const float* Wk    = (const float*)d_in[3];
    const float* Wv    = (const float*)d_in[4];
    const float* Wp    = (const float*)d_in[5];
    const float* bp    = (const float*)d_in[6];
    float* out = (float*)d_out;

    char* ws = (char*)d_ws;
    size_t off = 0;
    unsigned short* khi  = (unsigned short*)(ws + off); off += (size_t)B_ * S_ * C_ * 2;
    unsigned short* klo  = (unsigned short*)(ws + off); off += (size_t)B_ * S_ * C_ * 2;
    float* qk            = (float*)(ws + off);          off += (size_t)B_ * H_ * N_ * C_ * 4;
    unsigned short* qkhi = (unsigned short*)(ws + off); off += (size_t)B_ * H_ * N_ * C_ * 2;
    unsigned short* qklo = (unsigned short*)(ws + off); off += (size_t)B_ * H_ * N_ * C_ * 2;
    unsigned int* idx    = (unsigned int*)(ws + off);   off += (size_t)B_ * H_ * S_ * 4;
    unsigned int* order  = (unsigned int*)(ws + off);   off += (size_t)B_ * H_ * S_ * 4;
    unsigned int* offs   = (unsigned int*)(ws + off);   off += (size_t)B_ * H_ * 65 * 4;
    float* gpart         = (float*)(ws + off);          off += (size_t)B_ * H_ * 2 * N_ * C_ * 4;
    float* gvn           = (float*)(ws + off);          off += (size_t)B_ * H_ * N_ * DH_ * 4;
    unsigned int* fcnt   = (unsigned int*)(ws + off);   off += 256;
    unsigned int* flist  = (unsigned int*)(ws + off);   off += (size_t)LISTCAP * 4;

    hipMemsetAsync(fcnt, 0, 256, stream);

    prep_kernel<<<(B_ * S_ * C_ / 8) / 256, 256, 0, stream>>>(key, khi, klo);
    qk_fused_kernel<<<dim3(N_ / 4, B_), 384, 0, stream>>>(query, Wq, Wk, qk, qkhi, qklo);
    attn_kernel<<<dim3(S_ / 256, H_, B_), 512, 0, stream>>>(qkhi, qklo, khi, klo, idx, fcnt, flist);
    fixup_kernel<<<256, 256, 0, stream>>>(qk, key, flist, fcnt, idx);
    hist_build_kernel<<<B_ * H_, 256, 0, stream>>>(idx, offs, order);
    agg2_kernel<<<dim3(32, H_, B_), 256, 0, stream>>>(khi, order, offs, gpart);
    gv_kernel<<<dim3(16, H_, B_), 256, 0, stream>>>(gpart, Wv, gvn);
    out_kernel<<<B_ * N_, 384, 0, stream>>>(gvn, Wp, bp, out);
}

// Round 3
// 543.849 us; speedup vs baseline: 1.6122x; 1.6122x over previous
//
#include <hip/hip_runtime.h>
#include <hip/hip_bf16.h>
#include <stdint.h>

#define B_ 16
#define N_ 64
#define S_ 4096
#define C_ 384
#define H_ 6
#define DH_ 64
#define SCALE_ 0.125f
#define TAU_ 2e-4f
#define LISTCAP 262144

typedef __attribute__((ext_vector_type(8))) short bf16x8;
typedef __attribute__((ext_vector_type(4))) float f32x4;

static __device__ __forceinline__ unsigned short f2bf(float x) {
    union { float f; unsigned u; } v; v.f = x;
    unsigned r = v.u + 0x7FFFu + ((v.u >> 16) & 1u);
    return (unsigned short)(r >> 16);
}
static __device__ __forceinline__ float bf2f(unsigned short b) {
    union { unsigned u; float f; } v; v.u = ((unsigned)b) << 16; return v.f;
}
static __device__ __forceinline__ float bfu_lo(unsigned u) {
    union { unsigned u; float f; } v; v.u = u << 16; return v.f;
}
static __device__ __forceinline__ float bfu_hi(unsigned u) {
    union { unsigned u; float f; } v; v.u = u & 0xFFFF0000u; return v.f;
}

// async global->LDS, 16B/lane; LDS dest = wave-uniform base + lane*16
static __device__ __forceinline__ void gl_lds16(const void* g, void* l) {
    __builtin_amdgcn_global_load_lds(
        (const __attribute__((address_space(1))) unsigned int*)g,
        (__attribute__((address_space(3))) unsigned int*)l, 16, 0, 0);
}

// ---------------------------------------------------------------------------
// K0: prep — key -> khi/klo (bf16 hi + bf16 residual)
// ---------------------------------------------------------------------------
__global__ __launch_bounds__(256) void prep_kernel(const float* __restrict__ key,
                                                   unsigned short* __restrict__ khi,
                                                   unsigned short* __restrict__ klo) {
    size_t gid = (size_t)blockIdx.x * 256 + threadIdx.x;
    size_t base = gid * 8;
    float4 x0 = *(const float4*)(key + base);
    float4 x1 = *(const float4*)(key + base + 4);
    float xs[8] = { x0.x, x0.y, x0.z, x0.w, x1.x, x1.y, x1.z, x1.w };
    unsigned short hi[8], lo[8];
#pragma unroll
    for (int i = 0; i < 8; ++i) {
        hi[i] = f2bf(xs[i]);
        lo[i] = f2bf(xs[i] - bf2f(hi[i]));
    }
    *(bf16x8*)(khi + base) = *(bf16x8*)hi;
    *(bf16x8*)(klo + base) = *(bf16x8*)lo;
}

// ---------------------------------------------------------------------------
// K1: fused q-proj + qk (fp32 exact) + bf16 hi/lo split. 4 rows/block.
// ---------------------------------------------------------------------------
__global__ __launch_bounds__(384) void qk_fused_kernel(const float* __restrict__ query,
                                                       const float* __restrict__ Wq,
                                                       const float* __restrict__ Wk,
                                                       float* __restrict__ qk,
                                                       unsigned short* __restrict__ qkhi,
                                                       unsigned short* __restrict__ qklo) {
    __shared__ float qstage[4][C_];
    __shared__ float qrow[4][C_];
    int ng = blockIdx.x, b = blockIdx.y;
    int t = threadIdx.x;
    int n0 = ng * 4;
#pragma unroll
    for (int i = 0; i < 4; ++i)
        qstage[i][t] = query[((size_t)(b * N_ + n0 + i)) * C_ + t];
    __syncthreads();
    {
        float a[4];
#pragma unroll
        for (int i = 0; i < 4; ++i) a[i] = 0.f;
        const float4* wq = (const float4*)(Wq + (size_t)t * C_);
        for (int c4 = 0; c4 < C_ / 4; ++c4) {
            float4 w = wq[c4];
#pragma unroll
            for (int i = 0; i < 4; ++i)
                a[i] += qstage[i][c4 * 4 + 0] * w.x + qstage[i][c4 * 4 + 1] * w.y
                      + qstage[i][c4 * 4 + 2] * w.z + qstage[i][c4 * 4 + 3] * w.w;
        }
#pragma unroll
        for (int i = 0; i < 4; ++i) qrow[i][t] = a[i] * SCALE_;
    }
    __syncthreads();
    for (int h = 0; h < H_; ++h) {
        float a[4];
#pragma unroll
        for (int i = 0; i < 4; ++i) a[i] = 0.f;
        const float* wk = Wk + (size_t)h * DH_ * C_ + t;
#pragma unroll 4
        for (int d = 0; d < DH_; ++d) {
            float w = wk[(size_t)d * C_];
#pragma unroll
            for (int i = 0; i < 4; ++i) a[i] += qrow[i][h * DH_ + d] * w;
        }
#pragma unroll
        for (int i = 0; i < 4; ++i) {
            size_t o = ((size_t)(b * H_ + h) * N_ + n0 + i) * C_ + t;
            float v = a[i];
            qk[o] = v;
            unsigned short hi = f2bf(v);
            qkhi[o] = hi;
            qklo[o] = f2bf(v - bf2f(hi));
        }
    }
}

// ---------------------------------------------------------------------------
// K2: logits via 3-pass bf16 MFMA + argmax. 64n x 128 tokens per block.
// ROUND-THIS: revert r1/r2 (dbuf -> occupancy cliff; forced launch_bounds
// -> acc spill, 946MB scratch writes). Instead shrink BOTH footprints:
// B-tile 256->128 tokens. LDS 40KB->24KB (6 blocks/CU cap = 24 waves/CU);
// acc[2][8]->acc[2][4] (64->32 VGPR, expect ~90-100 total -> ~20 waves/CU).
// No min-waves forcing — allocator free, no spill possible. Same 4-wave
// structure, same granule/swizzle geometry (granule = 16 rows x 32 cols),
// single-buffered. Worst case (VGPR > 102) == round-0's 16 waves/CU.
// ---------------------------------------------------------------------------
__global__ __launch_bounds__(256) void attn_kernel(const unsigned short* __restrict__ qkhi,
                                                   const unsigned short* __restrict__ qklo,
                                                   const unsigned short* __restrict__ khi,
                                                   const unsigned short* __restrict__ klo,
                                                   unsigned int* __restrict__ idx,
                                                   unsigned int* __restrict__ flag_cnt,
                                                   unsigned int* __restrict__ flag_list) {
    __shared__ __align__(16) unsigned short sAhi[64 * 32];
    __shared__ __align__(16) unsigned short sAlo[64 * 32];
    __shared__ __align__(16) unsigned short sBhi[128 * 32];
    __shared__ __align__(16) unsigned short sBlo[128 * 32];
    int tid = threadIdx.x;
    int w = tid >> 6, l = tid & 63;          // w in 0..3
    int wm = w >> 1, wn = w & 1;             // 2 x 2 wave grid (32q x 64tok each)
    int q4 = l >> 4, lm = l & 15;
    int s0 = blockIdx.x * 128;
    int h = blockIdx.y, b = blockIdx.z;
    size_t kbK = ((size_t)b * S_ + s0) * C_;
    size_t kbA = (size_t)(b * H_ + h) * N_ * C_;
    int trow16 = l >> 2;
    int tquart = ((l & 3) ^ ((l >> 3) & 3)) * 8;
    int sw = (q4 ^ ((lm >> 1) & 3)) * 8;

    f32x4 acc[2][4];
#pragma unroll
    for (int tm = 0; tm < 2; ++tm)
#pragma unroll
        for (int nt = 0; nt < 4; ++nt) acc[tm][nt] = (f32x4)0.f;

    for (int kc = 0; kc < C_; kc += 32) {
        __syncthreads();
        // 24 granules (1KB each: 16 rows x 32 cols bf16): 8 Bhi, 8 Blo, 4 Ahi, 4 Alo
#pragma unroll
        for (int i = 0; i < 6; ++i) {
            int gid = w * 6 + i;
            if (gid < 8) {
                gl_lds16(khi + kbK + (size_t)(gid * 16 + trow16) * C_ + kc + tquart,
                         (char*)sBhi + gid * 1024);
            } else if (gid < 16) {
                int g2 = gid - 8;
                gl_lds16(klo + kbK + (size_t)(g2 * 16 + trow16) * C_ + kc + tquart,
                         (char*)sBlo + g2 * 1024);
            } else if (gid < 20) {
                int g2 = gid - 16;
                gl_lds16(qkhi + kbA + (size_t)(g2 * 16 + trow16) * C_ + kc + tquart,
                         (char*)sAhi + g2 * 1024);
            } else {
                int g2 = gid - 20;
                gl_lds16(qklo + kbA + (size_t)(g2 * 16 + trow16) * C_ + kc + tquart,
                         (char*)sAlo + g2 * 1024);
            }
        }
        __syncthreads();
        bf16x8 ah[2], al[2];
#pragma unroll
        for (int tm = 0; tm < 2; ++tm) {
            int ar = (wm * 32 + tm * 16 + lm) * 32 + sw;
            ah[tm] = *(const bf16x8*)&sAhi[ar];
            al[tm] = *(const bf16x8*)&sAlo[ar];
        }
#pragma unroll
        for (int nt = 0; nt < 4; ++nt) {
            int nr = ((wn * 4 + nt) * 16 + lm) * 32 + sw;
            bf16x8 bh = *(const bf16x8*)&sBhi[nr];
            bf16x8 bl = *(const bf16x8*)&sBlo[nr];
#pragma unroll
            for (int tm = 0; tm < 2; ++tm) {
                acc[tm][nt] = __builtin_amdgcn_mfma_f32_16x16x32_bf16(ah[tm], bh, acc[tm][nt], 0, 0, 0);
                acc[tm][nt] = __builtin_amdgcn_mfma_f32_16x16x32_bf16(ah[tm], bl, acc[tm][nt], 0, 0, 0);
                acc[tm][nt] = __builtin_amdgcn_mfma_f32_16x16x32_bf16(al[tm], bh, acc[tm][nt], 0, 0, 0);
            }
        }
    }
    __syncthreads();

    float* rm1 = (float*)sBhi;   // scratch aliases sBhi; safe after final barrier
    float* rm2 = rm1 + 256;      // 2 wm-halves x 128 tokens
    int* ri1 = (int*)(rm2 + 256);
    int* ri2 = ri1 + 256;

#pragma unroll
    for (int nt = 0; nt < 4; ++nt) {
        float m1 = -3.4e38f, m2 = -3.4e38f; int i1 = 0, i2 = 0;
#pragma unroll
        for (int tm = 0; tm < 2; ++tm)
#pragma unroll
            for (int r = 0; r < 4; ++r) {
                float v = acc[tm][nt][r];
                int row = wm * 32 + tm * 16 + q4 * 4 + r;
                if (v > m1) { m2 = m1; i2 = i1; m1 = v; i1 = row; }
                else if (v > m2) { m2 = v; i2 = row; }
            }
#pragma unroll
        for (int off = 16; off < 64; off <<= 1) {
            float om1 = __shfl_xor(m1, off), om2 = __shfl_xor(m2, off);
            int oi1 = __shfl_xor(i1, off), oi2 = __shfl_xor(i2, off);
            bool take = (om1 > m1) || (om1 == m1 && oi1 < i1);
            float w1 = take ? om1 : m1; int wi1 = take ? oi1 : i1;
            float l1 = take ? m1 : om1; int li1 = take ? i1 : oi1;
            float s2 = m2; int si2 = i2;
            if (om2 > s2) { s2 = om2; si2 = oi2; }
            if (l1 > s2) { s2 = l1; si2 = li1; }
            m1 = w1; i1 = wi1; m2 = s2; i2 = si2;
        }
        if (q4 == 0) {
            int cw = (wn * 4 + nt) * 16 + lm;      // token col 0..127
            rm1[wm * 128 + cw] = m1; rm2[wm * 128 + cw] = m2;
            ri1[wm * 128 + cw] = i1; ri2[wm * 128 + cw] = i2;
        }
    }
    __syncthreads();
    if (tid < 128) {
        float a1 = rm1[tid], a2 = rm2[tid];
        int ai1 = ri1[tid], ai2 = ri2[tid];
        float b1 = rm1[128 + tid], b2 = rm2[128 + tid];
        int bi1 = ri1[128 + tid], bi2 = ri2[128 + tid];
        float w1, s2; int wi1, wi2;
        if (b1 > a1) { w1 = b1; wi1 = bi1; s2 = a1; wi2 = ai1; if (b2 > s2) { s2 = b2; wi2 = bi2; } }
        else         { w1 = a1; wi1 = ai1; s2 = a2; wi2 = ai2; if (b1 > s2) { s2 = b1; wi2 = bi1; } }
        idx[(size_t)(b * H_ + h) * S_ + s0 + tid] = (unsigned)wi1;
        if (w1 - s2 < TAU_) {
            unsigned p = atomicAdd(flag_cnt, 1u);
            if (p < LISTCAP) {
                unsigned tok = (unsigned)((b * H_ + h) * S_ + s0 + tid);
                flag_list[p] = tok | ((unsigned)wi1 << 19) | ((unsigned)wi2 << 25);
            }
        }
    }
}

// ---------------------------------------------------------------------------
// K3: fixup — exact fp32 recompute of two candidate rows for near-ties
// ---------------------------------------------------------------------------
__global__ __launch_bounds__(256) void fixup_kernel(const float* __restrict__ qk,
                                                    const float* __restrict__ key,
                                                    const unsigned int* __restrict__ flag_list,
                                                    const unsigned int* __restrict__ flag_cnt,
                                                    unsigned int* __restrict__ idx) {
    int w = threadIdx.x >> 6, l = threadIdx.x & 63;
    unsigned total = flag_cnt[0];
    if (total > LISTCAP) total = LISTCAP;
    for (unsigned t = blockIdx.x * 4 + w; t < total; t += gridDim.x * 4) {
        unsigned e = flag_list[t];
        unsigned tok = e & 0x7FFFFu;
        int i1 = (int)((e >> 19) & 63u), i2 = (int)((e >> 25) & 63u);
        unsigned bh = tok >> 12;
        unsigned s = tok & 4095u;
        unsigned bb = bh / H_;
        int l32 = l & 31;
        const float* qrow = qk + ((size_t)bh * N_ + (l < 32 ? i1 : i2)) * C_ + l32 * 12;
        const float* krow = key + ((size_t)bb * S_ + s) * C_ + l32 * 12;
        float sum = 0.f;
#pragma unroll
        for (int c = 0; c < 12; ++c) sum += qrow[c] * krow[c];
#pragma unroll
        for (int off = 1; off < 32; off <<= 1) sum += __shfl_xor(sum, off);
        float d1 = __shfl(sum, 0);
        float d2 = __shfl(sum, 32);
        int win = (d2 > d1 || (d2 == d1 && i2 < i1)) ? i2 : i1;
        if (l == 0) idx[(size_t)bh * S_ + s] = (unsigned)win;
    }
}

// ---------------------------------------------------------------------------
// K4: hist_build — per (b,h): histogram -> scan -> counting-sort placement
// ---------------------------------------------------------------------------
__global__ __launch_bounds__(256) void hist_build_kernel(const unsigned int* __restrict__ idx,
                                                         unsigned int* __restrict__ offs,
                                                         unsigned int* __restrict__ order) {
    __shared__ unsigned int cnts[N_];
    __shared__ unsigned int pos[N_];
    int tid = threadIdx.x;
    int bh = blockIdx.x;
    if (tid < N_) cnts[tid] = 0u;
    __syncthreads();
    const unsigned int* idxp = idx + (size_t)bh * S_;
    for (int s = tid; s < S_; s += 256) atomicAdd(&cnts[idxp[s]], 1u);
    __syncthreads();
    if (tid < N_) {
        unsigned v = cnts[tid];
        unsigned x = v;
#pragma unroll
        for (int off = 1; off < 64; off <<= 1) {
            unsigned y = __shfl_up(x, off);
            if (tid >= off) x += y;
        }
        unsigned excl = x - v;
        pos[tid] = excl;
        offs[(size_t)bh * 65 + tid] = excl;
        if (tid == 63) offs[(size_t)bh * 65 + 64] = x;   // == S_
    }
    __syncthreads();
    unsigned int* op = order + (size_t)bh * S_;
    for (int s = tid; s < S_; s += 256) {
        unsigned g = idxp[s];
        unsigned p = atomicAdd(&pos[g], 1u);
        op[p] = (unsigned)s;
    }
}

// ---------------------------------------------------------------------------
// K5: agg2 — per (group, half): contiguous token list -> register accumulation
// ---------------------------------------------------------------------------
__global__ __launch_bounds__(256) void agg2_kernel(const unsigned short* __restrict__ khi,
                                                   const unsigned int* __restrict__ order,
                                                   const unsigned int* __restrict__ offs,
                                                   float* __restrict__ gpart) {
    int tid = threadIdx.x;
    int w = tid >> 6, l = tid & 63;
    int h = blockIdx.y, b = blockIdx.z;
    int bh = b * H_ + h;
    int wid = blockIdx.x * 4 + w;       // 0..127
    int g = wid >> 1, part = wid & 1;
    unsigned beg = offs[(size_t)bh * 65 + g];
    unsigned end = offs[(size_t)bh * 65 + g + 1];
    int cnt = (int)(end - beg);
    float inv = 1.f / ((float)cnt + 1.f);
    const unsigned int* op = order + (size_t)bh * S_ + beg;
    const unsigned int* kbase = (const unsigned int*)(khi + (size_t)b * S_ * C_);
    float a0 = 0.f, a1 = 0.f, a2 = 0.f, a3 = 0.f, a4 = 0.f, a5 = 0.f;
    for (int base = part * 64; base < cnt; base += 128) {
        int m = cnt - base; if (m > 64) m = 64;
        unsigned sv = (l < m) ? op[base + l] : 0u;
        for (int i = 0; i < m; ++i) {
            int s = (int)__shfl((int)sv, i);
            const unsigned int* kp = kbase + (size_t)s * (C_ / 2) + l * 3;
            unsigned u0 = kp[0], u1 = kp[1], u2 = kp[2];
            a0 += bfu_lo(u0); a1 += bfu_hi(u0);
            a2 += bfu_lo(u1); a3 += bfu_hi(u1);
            a4 += bfu_lo(u2); a5 += bfu_hi(u2);
        }
    }
    float* gp = gpart + (((size_t)bh * 2 + part) * N_ + g) * C_ + l * 6;
    float2 o0 = { a0 * inv, a1 * inv };
    float2 o1 = { a2 * inv, a3 * inv };
    float2 o2 = { a4 * inv, a5 * inv };
    ((float2*)gp)[0] = o0; ((float2*)gp)[1] = o1; ((float2*)gp)[2] = o2;
}

// ---------------------------------------------------------------------------
// K6: gv — ONE WAVE PER (bh, group): 6144 independent waves (24/CU), no
// serialized group loop. Lane d: dot(row, Wv[h*64+d]); LDS row reads are
// same-address broadcast (free); Wv is L2-resident.
// ---------------------------------------------------------------------------
__global__ __launch_bounds__(256) void gv_kernel(const float* __restrict__ gpart,
                                                 const float* __restrict__ Wv,
                                                 float* __restrict__ gvn) {
    __shared__ float rows[4][C_];
    int tid = threadIdx.x;
    int w = tid >> 6, l = tid & 63;
    int h = blockIdx.y, b = blockIdx.z;
    int bh = b * H_ + h;
    int g = blockIdx.x * 4 + w;
    const float* s0 = gpart + (((size_t)bh * 2 + 0) * N_ + g) * C_;
    const float* s1 = gpart + (((size_t)bh * 2 + 1) * N_ + g) * C_;
    for (int i = l; i < C_ / 4; i += 64) {
        float4 x = ((const float4*)s0)[i];
        float4 y = ((const float4*)s1)[i];
        float4 z = { x.x + y.x, x.y + y.y, x.z + y.z, x.w + y.w };
        *(float4*)&rows[w][i * 4] = z;
    }
    __syncthreads();   // one barrier; waves independent afterwards
    const float* wrow = Wv + (size_t)(h * DH_ + l) * C_;
    float acc = 0.f;
#pragma unroll 8
    for (int c4 = 0; c4 < C_ / 4; ++c4) {
        float4 a = *(const float4*)&rows[w][c4 * 4];
        float4 wv = *(const float4*)&wrow[c4 * 4];
        acc += a.x * wv.x + a.y * wv.y + a.z * wv.z + a.w * wv.w;
    }
    gvn[((size_t)bh * N_ + g) * DH_ + l] = acc;
}

// ---------------------------------------------------------------------------
// K7: out[b,n,j] = sum_{h,d} gvn[b,h,n,d] * Wp[j, h*64+d] + bp[j]
// ---------------------------------------------------------------------------
__global__ __launch_bounds__(384) void out_kernel(const float* __restrict__ gvn,
                                                  const float* __restrict__ Wp,
                                                  const float* __restrict__ bp,
                                                  float* __restrict__ out) {
    __shared__ float vals[C_];
    int bn = blockIdx.x;
    int b = bn >> 6, n = bn & 63;
    int t = threadIdx.x;
    int h = t >> 6, d = t & 63;
    vals[t] = gvn[((size_t)(b * H_ + h) * N_ + n) * DH_ + d];
    __syncthreads();
    const float4* w4 = (const float4*)(Wp + (size_t)t * C_);
    const float4* v4 = (const float4*)vals;
    float s = bp[t];
#pragma unroll 8
    for (int i = 0; i < C_ / 4; ++i) {
        float4 a = v4[i]; float4 w = w4[i];
        s += a.x * w.x + a.y * w.y + a.z * w.z + a.w * w.w;
    }
    out[(size_t)bn * C_ + t] = s;
}

// ---------------------------------------------------------------------------
extern "C" void kernel_launch(void* const* d_in, const int* in_sizes, int n_in,
                              void* d_out, int out_size, void* d_ws, size_t ws_size,
                              hipStream_t stream) {
    (void)in_sizes; (void)n_in; (void)out_size; (void)ws_size;
    const float* query = (const float*)d_in[0];
    const float* key   = (const float*)d_in[1];
    const float* Wq    = (const float*)d_in[2];
    const float* Wk    = (const float*)d_in[3];
    const float* Wv    = (const float*)d_in[4];
    const float* Wp    = (const float*)d_in[5];
    const float* bp    = (const float*)d_in[6];
    float* out = (float*)d_out;

    char* ws = (char*)d_ws;
    size_t off = 0;
    unsigned short* khi  = (unsigned short*)(ws + off); off += (size_t)B_ * S_ * C_ * 2;
    unsigned short* klo  = (unsigned short*)(ws + off); off += (size_t)B_ * S_ * C_ * 2;
    float* qk            = (float*)(ws + off);          off += (size_t)B_ * H_ * N_ * C_ * 4;
    unsigned short* qkhi = (unsigned short*)(ws + off); off += (size_t)B_ * H_ * N_ * C_ * 2;
    unsigned short* qklo = (unsigned short*)(ws + off); off += (size_t)B_ * H_ * N_ * C_ * 2;
    unsigned int* idx    = (unsigned int*)(ws + off);   off += (size_t)B_ * H_ * S_ * 4;
    unsigned int* order  = (unsigned int*)(ws + off);   off += (size_t)B_ * H_ * S_ * 4;
    unsigned int* offs   = (unsigned int*)(ws + off);   off += (size_t)B_ * H_ * 65 * 4;
    float* gpart         = (float*)(ws + off);          off += (size_t)B_ * H_ * 2 * N_ * C_ * 4;
    float* gvn           = (float*)(ws + off);          off += (size_t)B_ * H_ * N_ * DH_ * 4;
    unsigned int* fcnt   = (unsigned int*)(ws + off);   off += 256;
    unsigned int* flist  = (unsigned int*)(ws + off);   off += (size_t)LISTCAP * 4;

    hipMemsetAsync(fcnt, 0, 256, stream);

    prep_kernel<<<(B_ * S_ * C_ / 8) / 256, 256, 0, stream>>>(key, khi, klo);
    qk_fused_kernel<<<dim3(N_ / 4, B_), 384, 0, stream>>>(query, Wq, Wk, qk, qkhi, qklo);
    attn_kernel<<<dim3(S_ / 128, H_, B_), 256, 0, stream>>>(qkhi, qklo, khi, klo, idx, fcnt, flist);
    fixup_kernel<<<256, 256, 0, stream>>>(qk, key, flist, fcnt, idx);
    hist_build_kernel<<<B_ * H_, 256, 0, stream>>>(idx, offs, order);
    agg2_kernel<<<dim3(32, H_, B_), 256, 0, stream>>>(khi, order, offs, gpart);
    gv_kernel<<<dim3(16, H_, B_), 256, 0, stream>>>(gpart, Wv, gvn);
    out_kernel<<<B_ * N_, 384, 0, stream>>>(gvn, Wp, bp, out);
}

// Round 4
// 540.405 us; speedup vs baseline: 1.6225x; 1.0064x over previous
//
#include <hip/hip_runtime.h>
#include <hip/hip_bf16.h>
#include <stdint.h>

#define B_ 16
#define N_ 64
#define S_ 4096
#define C_ 384
#define H_ 6
#define DH_ 64
#define SCALE_ 0.125f
#define TAU_ 2e-4f
#define LISTCAP 262144

typedef __attribute__((ext_vector_type(8))) short bf16x8;
typedef __attribute__((ext_vector_type(4))) float f32x4;

static __device__ __forceinline__ unsigned short f2bf(float x) {
    union { float f; unsigned u; } v; v.f = x;
    unsigned r = v.u + 0x7FFFu + ((v.u >> 16) & 1u);
    return (unsigned short)(r >> 16);
}
static __device__ __forceinline__ float bf2f(unsigned short b) {
    union { unsigned u; float f; } v; v.u = ((unsigned)b) << 16; return v.f;
}
static __device__ __forceinline__ float bfu_lo(unsigned u) {
    union { unsigned u; float f; } v; v.u = u << 16; return v.f;
}
static __device__ __forceinline__ float bfu_hi(unsigned u) {
    union { unsigned u; float f; } v; v.u = u & 0xFFFF0000u; return v.f;
}

// async global->LDS, 16B/lane; LDS dest = wave-uniform base + lane*16
static __device__ __forceinline__ void gl_lds16(const void* g, void* l) {
    __builtin_amdgcn_global_load_lds(
        (const __attribute__((address_space(1))) unsigned int*)g,
        (__attribute__((address_space(3))) unsigned int*)l, 16, 0, 0);
}

// ---------------------------------------------------------------------------
// K0: prep — key -> khi/klo (bf16 hi + bf16 residual)
// ---------------------------------------------------------------------------
__global__ __launch_bounds__(256) void prep_kernel(const float* __restrict__ key,
                                                   unsigned short* __restrict__ khi,
                                                   unsigned short* __restrict__ klo) {
    size_t gid = (size_t)blockIdx.x * 256 + threadIdx.x;
    size_t base = gid * 8;
    float4 x0 = *(const float4*)(key + base);
    float4 x1 = *(const float4*)(key + base + 4);
    float xs[8] = { x0.x, x0.y, x0.z, x0.w, x1.x, x1.y, x1.z, x1.w };
    unsigned short hi[8], lo[8];
#pragma unroll
    for (int i = 0; i < 8; ++i) {
        hi[i] = f2bf(xs[i]);
        lo[i] = f2bf(xs[i] - bf2f(hi[i]));
    }
    *(bf16x8*)(khi + base) = *(bf16x8*)hi;
    *(bf16x8*)(klo + base) = *(bf16x8*)lo;
}

// ---------------------------------------------------------------------------
// K1: fused q-proj + qk (fp32 exact) + bf16 hi/lo split.
// ROUND-THIS: was the new top kernel (92 us, MfmaUtil=0, Occ=16%, 23x off
// the 157-TF vector roofline) — only 256 blocks, serial 6-head loop.
// Now grid (N/4, H, B) = 1536 blocks: per (n-tile, head) block, phase 1
// computes ONLY that head's 64 q-columns (4x64 outputs, thread t<256 does
// one 384-long float4 dot) -> zero redundant FLOPs vs before; phase 2 is
// the identical coalesced per-head qk loop. Summation order of both phases
// is bit-identical to the old kernel -> qk/qkhi/qklo bytes unchanged.
// Occupancy 6 waves/CU -> ~30 waves/CU (wave-cap), 6x block parallelism.
// ---------------------------------------------------------------------------
__global__ __launch_bounds__(384) void qk_fused_kernel(const float* __restrict__ query,
                                                       const float* __restrict__ Wq,
                                                       const float* __restrict__ Wk,
                                                       float* __restrict__ qk,
                                                       unsigned short* __restrict__ qkhi,
                                                       unsigned short* __restrict__ qklo) {
    __shared__ float qstage[4][C_];
    __shared__ float qv[4][DH_];
    int ng = blockIdx.x, h = blockIdx.y, b = blockIdx.z;
    int t = threadIdx.x;
    int n0 = ng * 4;
#pragma unroll
    for (int i = 0; i < 4; ++i)
        qstage[i][t] = query[((size_t)(b * N_ + n0 + i)) * C_ + t];
    __syncthreads();
    // phase 1: q-projection, this head's 64 columns only. 256 threads active.
    if (t < 256) {
        int i = t >> 6, d = t & 63;
        const float4* wq = (const float4*)(Wq + (size_t)(h * DH_ + d) * C_);
        float acc = 0.f;
#pragma unroll 4
        for (int c4 = 0; c4 < C_ / 4; ++c4) {
            float4 w = wq[c4];
            float4 q4 = *(const float4*)&qstage[i][c4 * 4];
            acc += q4.x * w.x + q4.y * w.y + q4.z * w.z + q4.w * w.w;
        }
        qv[i][d] = acc * SCALE_;
    }
    __syncthreads();
    // phase 2: qk[b,h,n,t] = sum_d qv[i][d] * Wk[h*64+d][t]  (coalesced in t)
    {
        float a[4];
#pragma unroll
        for (int i = 0; i < 4; ++i) a[i] = 0.f;
        const float* wk = Wk + (size_t)h * DH_ * C_ + t;
#pragma unroll 4
        for (int d = 0; d < DH_; ++d) {
            float w = wk[(size_t)d * C_];
#pragma unroll
            for (int i = 0; i < 4; ++i) a[i] += qv[i][d] * w;
        }
#pragma unroll
        for (int i = 0; i < 4; ++i) {
            size_t o = ((size_t)(b * H_ + h) * N_ + n0 + i) * C_ + t;
            float v = a[i];
            qk[o] = v;
            unsigned short hi = f2bf(v);
            qkhi[o] = hi;
            qklo[o] = f2bf(v - bf2f(hi));
        }
    }
}

// ---------------------------------------------------------------------------
// K2: logits via 3-pass bf16 MFMA + argmax. 64n x 128 tokens per block.
// (round-3 state: 24KB LDS, acc[2][4], 6 blocks/CU cap; known-good <92us)
// ---------------------------------------------------------------------------
__global__ __launch_bounds__(256) void attn_kernel(const unsigned short* __restrict__ qkhi,
                                                   const unsigned short* __restrict__ qklo,
                                                   const unsigned short* __restrict__ khi,
                                                   const unsigned short* __restrict__ klo,
                                                   unsigned int* __restrict__ idx,
                                                   unsigned int* __restrict__ flag_cnt,
                                                   unsigned int* __restrict__ flag_list) {
    __shared__ __align__(16) unsigned short sAhi[64 * 32];
    __shared__ __align__(16) unsigned short sAlo[64 * 32];
    __shared__ __align__(16) unsigned short sBhi[128 * 32];
    __shared__ __align__(16) unsigned short sBlo[128 * 32];
    int tid = threadIdx.x;
    int w = tid >> 6, l = tid & 63;          // w in 0..3
    int wm = w >> 1, wn = w & 1;             // 2 x 2 wave grid (32q x 64tok each)
    int q4 = l >> 4, lm = l & 15;
    int s0 = blockIdx.x * 128;
    int h = blockIdx.y, b = blockIdx.z;
    size_t kbK = ((size_t)b * S_ + s0) * C_;
    size_t kbA = (size_t)(b * H_ + h) * N_ * C_;
    int trow16 = l >> 2;
    int tquart = ((l & 3) ^ ((l >> 3) & 3)) * 8;
    int sw = (q4 ^ ((lm >> 1) & 3)) * 8;

    f32x4 acc[2][4];
#pragma unroll
    for (int tm = 0; tm < 2; ++tm)
#pragma unroll
        for (int nt = 0; nt < 4; ++nt) acc[tm][nt] = (f32x4)0.f;

    for (int kc = 0; kc < C_; kc += 32) {
        __syncthreads();
        // 24 granules (1KB each: 16 rows x 32 cols bf16): 8 Bhi, 8 Blo, 4 Ahi, 4 Alo
#pragma unroll
        for (int i = 0; i < 6; ++i) {
            int gid = w * 6 + i;
            if (gid < 8) {
                gl_lds16(khi + kbK + (size_t)(gid * 16 + trow16) * C_ + kc + tquart,
                         (char*)sBhi + gid * 1024);
            } else if (gid < 16) {
                int g2 = gid - 8;
                gl_lds16(klo + kbK + (size_t)(g2 * 16 + trow16) * C_ + kc + tquart,
                         (char*)sBlo + g2 * 1024);
            } else if (gid < 20) {
                int g2 = gid - 16;
                gl_lds16(qkhi + kbA + (size_t)(g2 * 16 + trow16) * C_ + kc + tquart,
                         (char*)sAhi + g2 * 1024);
            } else {
                int g2 = gid - 20;
                gl_lds16(qklo + kbA + (size_t)(g2 * 16 + trow16) * C_ + kc + tquart,
                         (char*)sAlo + g2 * 1024);
            }
        }
        __syncthreads();
        bf16x8 ah[2], al[2];
#pragma unroll
        for (int tm = 0; tm < 2; ++tm) {
            int ar = (wm * 32 + tm * 16 + lm) * 32 + sw;
            ah[tm] = *(const bf16x8*)&sAhi[ar];
            al[tm] = *(const bf16x8*)&sAlo[ar];
        }
#pragma unroll
        for (int nt = 0; nt < 4; ++nt) {
            int nr = ((wn * 4 + nt) * 16 + lm) * 32 + sw;
            bf16x8 bh = *(const bf16x8*)&sBhi[nr];
            bf16x8 bl = *(const bf16x8*)&sBlo[nr];
#pragma unroll
            for (int tm = 0; tm < 2; ++tm) {
                acc[tm][nt] = __builtin_amdgcn_mfma_f32_16x16x32_bf16(ah[tm], bh, acc[tm][nt], 0, 0, 0);
                acc[tm][nt] = __builtin_amdgcn_mfma_f32_16x16x32_bf16(ah[tm], bl, acc[tm][nt], 0, 0, 0);
                acc[tm][nt] = __builtin_amdgcn_mfma_f32_16x16x32_bf16(al[tm], bh, acc[tm][nt], 0, 0, 0);
            }
        }
    }
    __syncthreads();

    float* rm1 = (float*)sBhi;   // scratch aliases sBhi; safe after final barrier
    float* rm2 = rm1 + 256;      // 2 wm-halves x 128 tokens
    int* ri1 = (int*)(rm2 + 256);
    int* ri2 = ri1 + 256;

#pragma unroll
    for (int nt = 0; nt < 4; ++nt) {
        float m1 = -3.4e38f, m2 = -3.4e38f; int i1 = 0, i2 = 0;
#pragma unroll
        for (int tm = 0; tm < 2; ++tm)
#pragma unroll
            for (int r = 0; r < 4; ++r) {
                float v = acc[tm][nt][r];
                int row = wm * 32 + tm * 16 + q4 * 4 + r;
                if (v > m1) { m2 = m1; i2 = i1; m1 = v; i1 = row; }
                else if (v > m2) { m2 = v; i2 = row; }
            }
#pragma unroll
        for (int off = 16; off < 64; off <<= 1) {
            float om1 = __shfl_xor(m1, off), om2 = __shfl_xor(m2, off);
            int oi1 = __shfl_xor(i1, off), oi2 = __shfl_xor(i2, off);
            bool take = (om1 > m1) || (om1 == m1 && oi1 < i1);
            float w1 = take ? om1 : m1; int wi1 = take ? oi1 : i1;
            float l1 = take ? m1 : om1; int li1 = take ? i1 : oi1;
            float s2 = m2; int si2 = i2;
            if (om2 > s2) { s2 = om2; si2 = oi2; }
            if (l1 > s2) { s2 = l1; si2 = li1; }
            m1 = w1; i1 = wi1; m2 = s2; i2 = si2;
        }
        if (q4 == 0) {
            int cw = (wn * 4 + nt) * 16 + lm;      // token col 0..127
            rm1[wm * 128 + cw] = m1; rm2[wm * 128 + cw] = m2;
            ri1[wm * 128 + cw] = i1; ri2[wm * 128 + cw] = i2;
        }
    }
    __syncthreads();
    if (tid < 128) {
        float a1 = rm1[tid], a2 = rm2[tid];
        int ai1 = ri1[tid], ai2 = ri2[tid];
        float b1 = rm1[128 + tid], b2 = rm2[128 + tid];
        int bi1 = ri1[128 + tid], bi2 = ri2[128 + tid];
        float w1, s2; int wi1, wi2;
        if (b1 > a1) { w1 = b1; wi1 = bi1; s2 = a1; wi2 = ai1; if (b2 > s2) { s2 = b2; wi2 = bi2; } }
        else         { w1 = a1; wi1 = ai1; s2 = a2; wi2 = ai2; if (b1 > s2) { s2 = b1; wi2 = bi1; } }
        idx[(size_t)(b * H_ + h) * S_ + s0 + tid] = (unsigned)wi1;
        if (w1 - s2 < TAU_) {
            unsigned p = atomicAdd(flag_cnt, 1u);
            if (p < LISTCAP) {
                unsigned tok = (unsigned)((b * H_ + h) * S_ + s0 + tid);
                flag_list[p] = tok | ((unsigned)wi1 << 19) | ((unsigned)wi2 << 25);
            }
        }
    }
}

// ---------------------------------------------------------------------------
// K3: fixup — exact fp32 recompute of two candidate rows for near-ties
// ---------------------------------------------------------------------------
__global__ __launch_bounds__(256) void fixup_kernel(const float* __restrict__ qk,
                                                    const float* __restrict__ key,
                                                    const unsigned int* __restrict__ flag_list,
                                                    const unsigned int* __restrict__ flag_cnt,
                                                    unsigned int* __restrict__ idx) {
    int w = threadIdx.x >> 6, l = threadIdx.x & 63;
    unsigned total = flag_cnt[0];
    if (total > LISTCAP) total = LISTCAP;
    for (unsigned t = blockIdx.x * 4 + w; t < total; t += gridDim.x * 4) {
        unsigned e = flag_list[t];
        unsigned tok = e & 0x7FFFFu;
        int i1 = (int)((e >> 19) & 63u), i2 = (int)((e >> 25) & 63u);
        unsigned bh = tok >> 12;
        unsigned s = tok & 4095u;
        unsigned bb = bh / H_;
        int l32 = l & 31;
        const float* qrow = qk + ((size_t)bh * N_ + (l < 32 ? i1 : i2)) * C_ + l32 * 12;
        const float* krow = key + ((size_t)bb * S_ + s) * C_ + l32 * 12;
        float sum = 0.f;
#pragma unroll
        for (int c = 0; c < 12; ++c) sum += qrow[c] * krow[c];
#pragma unroll
        for (int off = 1; off < 32; off <<= 1) sum += __shfl_xor(sum, off);
        float d1 = __shfl(sum, 0);
        float d2 = __shfl(sum, 32);
        int win = (d2 > d1 || (d2 == d1 && i2 < i1)) ? i2 : i1;
        if (l == 0) idx[(size_t)bh * S_ + s] = (unsigned)win;
    }
}

// ---------------------------------------------------------------------------
// K4: hist_build — per (b,h): histogram -> scan -> counting-sort placement
// ---------------------------------------------------------------------------
__global__ __launch_bounds__(256) void hist_build_kernel(const unsigned int* __restrict__ idx,
                                                         unsigned int* __restrict__ offs,
                                                         unsigned int* __restrict__ order) {
    __shared__ unsigned int cnts[N_];
    __shared__ unsigned int pos[N_];
    int tid = threadIdx.x;
    int bh = blockIdx.x;
    if (tid < N_) cnts[tid] = 0u;
    __syncthreads();
    const unsigned int* idxp = idx + (size_t)bh * S_;
    for (int s = tid; s < S_; s += 256) atomicAdd(&cnts[idxp[s]], 1u);
    __syncthreads();
    if (tid < N_) {
        unsigned v = cnts[tid];
        unsigned x = v;
#pragma unroll
        for (int off = 1; off < 64; off <<= 1) {
            unsigned y = __shfl_up(x, off);
            if (tid >= off) x += y;
        }
        unsigned excl = x - v;
        pos[tid] = excl;
        offs[(size_t)bh * 65 + tid] = excl;
        if (tid == 63) offs[(size_t)bh * 65 + 64] = x;   // == S_
    }
    __syncthreads();
    unsigned int* op = order + (size_t)bh * S_;
    for (int s = tid; s < S_; s += 256) {
        unsigned g = idxp[s];
        unsigned p = atomicAdd(&pos[g], 1u);
        op[p] = (unsigned)s;
    }
}

// ---------------------------------------------------------------------------
// K5: agg2 — per (group, half): contiguous token list -> register accumulation
// ---------------------------------------------------------------------------
__global__ __launch_bounds__(256) void agg2_kernel(const unsigned short* __restrict__ khi,
                                                   const unsigned int* __restrict__ order,
                                                   const unsigned int* __restrict__ offs,
                                                   float* __restrict__ gpart) {
    int tid = threadIdx.x;
    int w = tid >> 6, l = tid & 63;
    int h = blockIdx.y, b = blockIdx.z;
    int bh = b * H_ + h;
    int wid = blockIdx.x * 4 + w;       // 0..127
    int g = wid >> 1, part = wid & 1;
    unsigned beg = offs[(size_t)bh * 65 + g];
    unsigned end = offs[(size_t)bh * 65 + g + 1];
    int cnt = (int)(end - beg);
    float inv = 1.f / ((float)cnt + 1.f);
    const unsigned int* op = order + (size_t)bh * S_ + beg;
    const unsigned int* kbase = (const unsigned int*)(khi + (size_t)b * S_ * C_);
    float a0 = 0.f, a1 = 0.f, a2 = 0.f, a3 = 0.f, a4 = 0.f, a5 = 0.f;
    for (int base = part * 64; base < cnt; base += 128) {
        int m = cnt - base; if (m > 64) m = 64;
        unsigned sv = (l < m) ? op[base + l] : 0u;
        for (int i = 0; i < m; ++i) {
            int s = (int)__shfl((int)sv, i);
            const unsigned int* kp = kbase + (size_t)s * (C_ / 2) + l * 3;
            unsigned u0 = kp[0], u1 = kp[1], u2 = kp[2];
            a0 += bfu_lo(u0); a1 += bfu_hi(u0);
            a2 += bfu_lo(u1); a3 += bfu_hi(u1);
            a4 += bfu_lo(u2); a5 += bfu_hi(u2);
        }
    }
    float* gp = gpart + (((size_t)bh * 2 + part) * N_ + g) * C_ + l * 6;
    float2 o0 = { a0 * inv, a1 * inv };
    float2 o1 = { a2 * inv, a3 * inv };
    float2 o2 = { a4 * inv, a5 * inv };
    ((float2*)gp)[0] = o0; ((float2*)gp)[1] = o1; ((float2*)gp)[2] = o2;
}

// ---------------------------------------------------------------------------
// K6: gv — ONE WAVE PER (bh, group): 6144 independent waves (24/CU), no
// serialized group loop. Lane d: dot(row, Wv[h*64+d]); LDS row reads are
// same-address broadcast (free); Wv is L2-resident.
// ---------------------------------------------------------------------------
__global__ __launch_bounds__(256) void gv_kernel(const float* __restrict__ gpart,
                                                 const float* __restrict__ Wv,
                                                 float* __restrict__ gvn) {
    __shared__ float rows[4][C_];
    int tid = threadIdx.x;
    int w = tid >> 6, l = tid & 63;
    int h = blockIdx.y, b = blockIdx.z;
    int bh = b * H_ + h;
    int g = blockIdx.x * 4 + w;
    const float* s0 = gpart + (((size_t)bh * 2 + 0) * N_ + g) * C_;
    const float* s1 = gpart + (((size_t)bh * 2 + 1) * N_ + g) * C_;
    for (int i = l; i < C_ / 4; i += 64) {
        float4 x = ((const float4*)s0)[i];
        float4 y = ((const float4*)s1)[i];
        float4 z = { x.x + y.x, x.y + y.y, x.z + y.z, x.w + y.w };
        *(float4*)&rows[w][i * 4] = z;
    }
    __syncthreads();   // one barrier; waves independent afterwards
    const float* wrow = Wv + (size_t)(h * DH_ + l) * C_;
    float acc = 0.f;
#pragma unroll 8
    for (int c4 = 0; c4 < C_ / 4; ++c4) {
        float4 a = *(const float4*)&rows[w][c4 * 4];
        float4 wv = *(const float4*)&wrow[c4 * 4];
        acc += a.x * wv.x + a.y * wv.y + a.z * wv.z + a.w * wv.w;
    }
    gvn[((size_t)bh * N_ + g) * DH_ + l] = acc;
}

// ---------------------------------------------------------------------------
// K7: out[b,n,j] = sum_{h,d} gvn[b,h,n,d] * Wp[j, h*64+d] + bp[j]
// ---------------------------------------------------------------------------
__global__ __launch_bounds__(384) void out_kernel(const float* __restrict__ gvn,
                                                  const float* __restrict__ Wp,
                                                  const float* __restrict__ bp,
                                                  float* __restrict__ out) {
    __shared__ float vals[C_];
    int bn = blockIdx.x;
    int b = bn >> 6, n = bn & 63;
    int t = threadIdx.x;
    int h = t >> 6, d = t & 63;
    vals[t] = gvn[((size_t)(b * H_ + h) * N_ + n) * DH_ + d];
    __syncthreads();
    const float4* w4 = (const float4*)(Wp + (size_t)t * C_);
    const float4* v4 = (const float4*)vals;
    float s = bp[t];
#pragma unroll 8
    for (int i = 0; i < C_ / 4; ++i) {
        float4 a = v4[i]; float4 w = w4[i];
        s += a.x * w.x + a.y * w.y + a.z * w.z + a.w * w.w;
    }
    out[(size_t)bn * C_ + t] = s;
}

// ---------------------------------------------------------------------------
extern "C" void kernel_launch(void* const* d_in, const int* in_sizes, int n_in,
                              void* d_out, int out_size, void* d_ws, size_t ws_size,
                              hipStream_t stream) {
    (void)in_sizes; (void)n_in; (void)out_size; (void)ws_size;
    const float* query = (const float*)d_in[0];
    const float* key   = (const float*)d_in[1];
    const float* Wq    = (const float*)d_in[2];
    const float* Wk    = (const float*)d_in[3];
    const float* Wv    = (const float*)d_in[4];
    const float* Wp    = (const float*)d_in[5];
    const float* bp    = (const float*)d_in[6];
    float* out = (float*)d_out;

    char* ws = (char*)d_ws;
    size_t off = 0;
    unsigned short* khi  = (unsigned short*)(ws + off); off += (size_t)B_ * S_ * C_ * 2;
    unsigned short* klo  = (unsigned short*)(ws + off); off += (size_t)B_ * S_ * C_ * 2;
    float* qk            = (float*)(ws + off);          off += (size_t)B_ * H_ * N_ * C_ * 4;
    unsigned short* qkhi = (unsigned short*)(ws + off); off += (size_t)B_ * H_ * N_ * C_ * 2;
    unsigned short* qklo = (unsigned short*)(ws + off); off += (size_t)B_ * H_ * N_ * C_ * 2;
    unsigned int* idx    = (unsigned int*)(ws + off);   off += (size_t)B_ * H_ * S_ * 4;
    unsigned int* order  = (unsigned int*)(ws + off);   off += (size_t)B_ * H_ * S_ * 4;
    unsigned int* offs   = (unsigned int*)(ws + off);   off += (size_t)B_ * H_ * 65 * 4;
    float* gpart         = (float*)(ws + off);          off += (size_t)B_ * H_ * 2 * N_ * C_ * 4;
    float* gvn           = (float*)(ws + off);          off += (size_t)B_ * H_ * N_ * DH_ * 4;
    unsigned int* fcnt   = (unsigned int*)(ws + off);   off += 256;
    unsigned int* flist  = (unsigned int*)(ws + off);   off += (size_t)LISTCAP * 4;

    hipMemsetAsync(fcnt, 0, 256, stream);

    prep_kernel<<<(B_ * S_ * C_ / 8) / 256, 256, 0, stream>>>(key, khi, klo);
    qk_fused_kernel<<<dim3(N_ / 4, H_, B_), 384, 0, stream>>>(query, Wq, Wk, qk, qkhi, qklo);
    attn_kernel<<<dim3(S_ / 128, H_, B_), 256, 0, stream>>>(qkhi, qklo, khi, klo, idx, fcnt, flist);
    fixup_kernel<<<256, 256, 0, stream>>>(qk, key, flist, fcnt, idx);
    hist_build_kernel<<<B_ * H_, 256, 0, stream>>>(idx, offs, order);
    agg2_kernel<<<dim3(32, H_, B_), 256, 0, stream>>>(khi, order, offs, gpart);
    gv_kernel<<<dim3(16, H_, B_), 256, 0, stream>>>(gpart, Wv, gvn);
    out_kernel<<<B_ * N_, 384, 0, stream>>>(gvn, Wp, bp, out);
}

// Round 5
// 480.596 us; speedup vs baseline: 1.8244x; 1.1244x over previous
//
#include <hip/hip_runtime.h>
#include <hip/hip_bf16.h>
#include <stdint.h>

#define B_ 16
#define N_ 64
#define S_ 4096
#define C_ 384
#define H_ 6
#define DH_ 64
#define SCALE_ 0.125f
#define TAU_ 2e-4f
#define LISTCAP 262144

typedef __attribute__((ext_vector_type(8))) short bf16x8;
typedef __attribute__((ext_vector_type(4))) float f32x4;

static __device__ __forceinline__ unsigned short f2bf(float x) {
    union { float f; unsigned u; } v; v.f = x;
    unsigned r = v.u + 0x7FFFu + ((v.u >> 16) & 1u);
    return (unsigned short)(r >> 16);
}
static __device__ __forceinline__ float bf2f(unsigned short b) {
    union { unsigned u; float f; } v; v.u = ((unsigned)b) << 16; return v.f;
}
static __device__ __forceinline__ float bfu_lo(unsigned u) {
    union { unsigned u; float f; } v; v.u = u << 16; return v.f;
}
static __device__ __forceinline__ float bfu_hi(unsigned u) {
    union { unsigned u; float f; } v; v.u = u & 0xFFFF0000u; return v.f;
}

// async global->LDS, 16B/lane; LDS dest = wave-uniform base + lane*16
static __device__ __forceinline__ void gl_lds16(const void* g, void* l) {
    __builtin_amdgcn_global_load_lds(
        (const __attribute__((address_space(1))) unsigned int*)g,
        (__attribute__((address_space(3))) unsigned int*)l, 16, 0, 0);
}

// ---------------------------------------------------------------------------
// K0+K1 fused: prep (key -> khi/klo) + q-proj/fold-Wk. Independent inputs,
// block-granular branch. Rationale (r4 post-mortem): bench total tracks the
// SERIAL DISPATCH CHAIN, not kernel interiors; prep (HBM-bound) and qk
// (latency-bound) overlap under co-residency, and one ~90us-class dispatch
// disappears. qk part: 8 rows/block (was 4), phase-1 thread computes 2 rows
// sharing each Wq float4 (2x FLOP/load), phase-2 has 8 FMA per Wk load.
// Per-row dot order identical to prior rounds -> qk/qkhi/qklo bytes identical.
// ---------------------------------------------------------------------------
#define PREP_BLOCKS 8192   // 8192 * 384 threads * 8 elems = 16*4096*384
#define QK_BLOCKS   (8 * H_ * B_)   // N_/8 x H x B = 768

__global__ __launch_bounds__(384) void prepqk_kernel(const float* __restrict__ key,
                                                     unsigned short* __restrict__ khi,
                                                     unsigned short* __restrict__ klo,
                                                     const float* __restrict__ query,
                                                     const float* __restrict__ Wq,
                                                     const float* __restrict__ Wk,
                                                     float* __restrict__ qk,
                                                     unsigned short* __restrict__ qkhi,
                                                     unsigned short* __restrict__ qklo) {
    if (blockIdx.x < PREP_BLOCKS) {
        size_t gid = (size_t)blockIdx.x * 384 + threadIdx.x;
        size_t base = gid * 8;
        float4 x0 = *(const float4*)(key + base);
        float4 x1 = *(const float4*)(key + base + 4);
        float xs[8] = { x0.x, x0.y, x0.z, x0.w, x1.x, x1.y, x1.z, x1.w };
        unsigned short hi[8], lo[8];
#pragma unroll
        for (int i = 0; i < 8; ++i) {
            hi[i] = f2bf(xs[i]);
            lo[i] = f2bf(xs[i] - bf2f(hi[i]));
        }
        *(bf16x8*)(khi + base) = *(bf16x8*)hi;
        *(bf16x8*)(klo + base) = *(bf16x8*)lo;
        return;
    }
    // ---- qk part ----
    __shared__ float qstage[8][C_];
    __shared__ float qv[8][DH_];
    int e = blockIdx.x - PREP_BLOCKS;           // 0..767
    int ng = e & 7;                             // 8 row-tiles
    int h = (e >> 3) % H_;
    int b = e / (8 * H_);
    int t = threadIdx.x;
    int n0 = ng * 8;
#pragma unroll
    for (int i = 0; i < 8; ++i)
        qstage[i][t] = query[((size_t)(b * N_ + n0 + i)) * C_ + t];
    __syncthreads();
    // phase 1: q-projection for this head's 64 cols; thread t<256 computes
    // rows i0 and i0+4 (shares the Wq row load). Per-row dot order unchanged.
    if (t < 256) {
        int i0 = t >> 6, d = t & 63;
        const float4* wq = (const float4*)(Wq + (size_t)(h * DH_ + d) * C_);
        float accA = 0.f, accB = 0.f;
#pragma unroll 4
        for (int c4 = 0; c4 < C_ / 4; ++c4) {
            float4 w = wq[c4];
            float4 qa = *(const float4*)&qstage[i0][c4 * 4];
            float4 qb = *(const float4*)&qstage[i0 + 4][c4 * 4];
            accA += qa.x * w.x + qa.y * w.y + qa.z * w.z + qa.w * w.w;
            accB += qb.x * w.x + qb.y * w.y + qb.z * w.z + qb.w * w.w;
        }
        qv[i0][d] = accA * SCALE_;
        qv[i0 + 4][d] = accB * SCALE_;
    }
    __syncthreads();
    // phase 2: qk[n,t] = sum_d qv[n][d] * Wk[h*64+d][t], 8 FMA per load
    {
        float a[8];
#pragma unroll
        for (int i = 0; i < 8; ++i) a[i] = 0.f;
        const float* wk = Wk + (size_t)h * DH_ * C_ + t;
#pragma unroll 4
        for (int d = 0; d < DH_; ++d) {
            float w = wk[(size_t)d * C_];
#pragma unroll
            for (int i = 0; i < 8; ++i) a[i] += qv[i][d] * w;
        }
#pragma unroll
        for (int i = 0; i < 8; ++i) {
            size_t o = ((size_t)(b * H_ + h) * N_ + n0 + i) * C_ + t;
            float v = a[i];
            qk[o] = v;
            unsigned short hi = f2bf(v);
            qkhi[o] = hi;
            qklo[o] = f2bf(v - bf2f(hi));
        }
    }
}

// ---------------------------------------------------------------------------
// K2: logits via 3-pass bf16 MFMA + argmax. 64n x 128 tokens per block.
// (round-3 state, known-good: 24KB LDS, acc[2][4], VGPR 72, Occ 30%)
// ---------------------------------------------------------------------------
__global__ __launch_bounds__(256) void attn_kernel(const unsigned short* __restrict__ qkhi,
                                                   const unsigned short* __restrict__ qklo,
                                                   const unsigned short* __restrict__ khi,
                                                   const unsigned short* __restrict__ klo,
                                                   unsigned int* __restrict__ idx,
                                                   unsigned int* __restrict__ flag_cnt,
                                                   unsigned int* __restrict__ flag_list) {
    __shared__ __align__(16) unsigned short sAhi[64 * 32];
    __shared__ __align__(16) unsigned short sAlo[64 * 32];
    __shared__ __align__(16) unsigned short sBhi[128 * 32];
    __shared__ __align__(16) unsigned short sBlo[128 * 32];
    int tid = threadIdx.x;
    int w = tid >> 6, l = tid & 63;          // w in 0..3
    int wm = w >> 1, wn = w & 1;             // 2 x 2 wave grid (32q x 64tok each)
    int q4 = l >> 4, lm = l & 15;
    int s0 = blockIdx.x * 128;
    int h = blockIdx.y, b = blockIdx.z;
    size_t kbK = ((size_t)b * S_ + s0) * C_;
    size_t kbA = (size_t)(b * H_ + h) * N_ * C_;
    int trow16 = l >> 2;
    int tquart = ((l & 3) ^ ((l >> 3) & 3)) * 8;
    int sw = (q4 ^ ((lm >> 1) & 3)) * 8;

    f32x4 acc[2][4];
#pragma unroll
    for (int tm = 0; tm < 2; ++tm)
#pragma unroll
        for (int nt = 0; nt < 4; ++nt) acc[tm][nt] = (f32x4)0.f;

    for (int kc = 0; kc < C_; kc += 32) {
        __syncthreads();
        // 24 granules (1KB each: 16 rows x 32 cols bf16): 8 Bhi, 8 Blo, 4 Ahi, 4 Alo
#pragma unroll
        for (int i = 0; i < 6; ++i) {
            int gid = w * 6 + i;
            if (gid < 8) {
                gl_lds16(khi + kbK + (size_t)(gid * 16 + trow16) * C_ + kc + tquart,
                         (char*)sBhi + gid * 1024);
            } else if (gid < 16) {
                int g2 = gid - 8;
                gl_lds16(klo + kbK + (size_t)(g2 * 16 + trow16) * C_ + kc + tquart,
                         (char*)sBlo + g2 * 1024);
            } else if (gid < 20) {
                int g2 = gid - 16;
                gl_lds16(qkhi + kbA + (size_t)(g2 * 16 + trow16) * C_ + kc + tquart,
                         (char*)sAhi + g2 * 1024);
            } else {
                int g2 = gid - 20;
                gl_lds16(qklo + kbA + (size_t)(g2 * 16 + trow16) * C_ + kc + tquart,
                         (char*)sAlo + g2 * 1024);
            }
        }
        __syncthreads();
        bf16x8 ah[2], al[2];
#pragma unroll
        for (int tm = 0; tm < 2; ++tm) {
            int ar = (wm * 32 + tm * 16 + lm) * 32 + sw;
            ah[tm] = *(const bf16x8*)&sAhi[ar];
            al[tm] = *(const bf16x8*)&sAlo[ar];
        }
#pragma unroll
        for (int nt = 0; nt < 4; ++nt) {
            int nr = ((wn * 4 + nt) * 16 + lm) * 32 + sw;
            bf16x8 bh = *(const bf16x8*)&sBhi[nr];
            bf16x8 bl = *(const bf16x8*)&sBlo[nr];
#pragma unroll
            for (int tm = 0; tm < 2; ++tm) {
                acc[tm][nt] = __builtin_amdgcn_mfma_f32_16x16x32_bf16(ah[tm], bh, acc[tm][nt], 0, 0, 0);
                acc[tm][nt] = __builtin_amdgcn_mfma_f32_16x16x32_bf16(ah[tm], bl, acc[tm][nt], 0, 0, 0);
                acc[tm][nt] = __builtin_amdgcn_mfma_f32_16x16x32_bf16(al[tm], bh, acc[tm][nt], 0, 0, 0);
            }
        }
    }
    __syncthreads();

    float* rm1 = (float*)sBhi;   // scratch aliases sBhi; safe after final barrier
    float* rm2 = rm1 + 256;      // 2 wm-halves x 128 tokens
    int* ri1 = (int*)(rm2 + 256);
    int* ri2 = ri1 + 256;

#pragma unroll
    for (int nt = 0; nt < 4; ++nt) {
        float m1 = -3.4e38f, m2 = -3.4e38f; int i1 = 0, i2 = 0;
#pragma unroll
        for (int tm = 0; tm < 2; ++tm)
#pragma unroll
            for (int r = 0; r < 4; ++r) {
                float v = acc[tm][nt][r];
                int row = wm * 32 + tm * 16 + q4 * 4 + r;
                if (v > m1) { m2 = m1; i2 = i1; m1 = v; i1 = row; }
                else if (v > m2) { m2 = v; i2 = row; }
            }
#pragma unroll
        for (int off = 16; off < 64; off <<= 1) {
            float om1 = __shfl_xor(m1, off), om2 = __shfl_xor(m2, off);
            int oi1 = __shfl_xor(i1, off), oi2 = __shfl_xor(i2, off);
            bool take = (om1 > m1) || (om1 == m1 && oi1 < i1);
            float w1 = take ? om1 : m1; int wi1 = take ? oi1 : i1;
            float l1 = take ? m1 : om1; int li1 = take ? i1 : oi1;
            float s2 = m2; int si2 = i2;
            if (om2 > s2) { s2 = om2; si2 = oi2; }
            if (l1 > s2) { s2 = l1; si2 = li1; }
            m1 = w1; i1 = wi1; m2 = s2; i2 = si2;
        }
        if (q4 == 0) {
            int cw = (wn * 4 + nt) * 16 + lm;      // token col 0..127
            rm1[wm * 128 + cw] = m1; rm2[wm * 128 + cw] = m2;
            ri1[wm * 128 + cw] = i1; ri2[wm * 128 + cw] = i2;
        }
    }
    __syncthreads();
    if (tid < 128) {
        float a1 = rm1[tid], a2 = rm2[tid];
        int ai1 = ri1[tid], ai2 = ri2[tid];
        float b1 = rm1[128 + tid], b2 = rm2[128 + tid];
        int bi1 = ri1[128 + tid], bi2 = ri2[128 + tid];
        float w1, s2; int wi1, wi2;
        if (b1 > a1) { w1 = b1; wi1 = bi1; s2 = a1; wi2 = ai1; if (b2 > s2) { s2 = b2; wi2 = bi2; } }
        else         { w1 = a1; wi1 = ai1; s2 = a2; wi2 = ai2; if (b1 > s2) { s2 = b1; wi2 = bi1; } }
        idx[(size_t)(b * H_ + h) * S_ + s0 + tid] = (unsigned)wi1;
        if (w1 - s2 < TAU_) {
            unsigned p = atomicAdd(flag_cnt, 1u);
            if (p < LISTCAP) {
                unsigned tok = (unsigned)((b * H_ + h) * S_ + s0 + tid);
                flag_list[p] = tok | ((unsigned)wi1 << 19) | ((unsigned)wi2 << 25);
            }
        }
    }
}

// ---------------------------------------------------------------------------
// K3: fixup — exact fp32 recompute of two candidate rows for near-ties
// ---------------------------------------------------------------------------
__global__ __launch_bounds__(256) void fixup_kernel(const float* __restrict__ qk,
                                                    const float* __restrict__ key,
                                                    const unsigned int* __restrict__ flag_list,
                                                    const unsigned int* __restrict__ flag_cnt,
                                                    unsigned int* __restrict__ idx) {
    int w = threadIdx.x >> 6, l = threadIdx.x & 63;
    unsigned total = flag_cnt[0];
    if (total > LISTCAP) total = LISTCAP;
    for (unsigned t = blockIdx.x * 4 + w; t < total; t += gridDim.x * 4) {
        unsigned e = flag_list[t];
        unsigned tok = e & 0x7FFFFu;
        int i1 = (int)((e >> 19) & 63u), i2 = (int)((e >> 25) & 63u);
        unsigned bh = tok >> 12;
        unsigned s = tok & 4095u;
        unsigned bb = bh / H_;
        int l32 = l & 31;
        const float* qrow = qk + ((size_t)bh * N_ + (l < 32 ? i1 : i2)) * C_ + l32 * 12;
        const float* krow = key + ((size_t)bb * S_ + s) * C_ + l32 * 12;
        float sum = 0.f;
#pragma unroll
        for (int c = 0; c < 12; ++c) sum += qrow[c] * krow[c];
#pragma unroll
        for (int off = 1; off < 32; off <<= 1) sum += __shfl_xor(sum, off);
        float d1 = __shfl(sum, 0);
        float d2 = __shfl(sum, 32);
        int win = (d2 > d1 || (d2 == d1 && i2 < i1)) ? i2 : i1;
        if (l == 0) idx[(size_t)bh * S_ + s] = (unsigned)win;
    }
}

// ---------------------------------------------------------------------------
// K4: hist_build — per (b,h): histogram -> scan -> counting-sort placement
// ---------------------------------------------------------------------------
__global__ __launch_bounds__(256) void hist_build_kernel(const unsigned int* __restrict__ idx,
                                                         unsigned int* __restrict__ offs,
                                                         unsigned int* __restrict__ order) {
    __shared__ unsigned int cnts[N_];
    __shared__ unsigned int pos[N_];
    int tid = threadIdx.x;
    int bh = blockIdx.x;
    if (tid < N_) cnts[tid] = 0u;
    __syncthreads();
    const unsigned int* idxp = idx + (size_t)bh * S_;
    for (int s = tid; s < S_; s += 256) atomicAdd(&cnts[idxp[s]], 1u);
    __syncthreads();
    if (tid < N_) {
        unsigned v = cnts[tid];
        unsigned x = v;
#pragma unroll
        for (int off = 1; off < 64; off <<= 1) {
            unsigned y = __shfl_up(x, off);
            if (tid >= off) x += y;
        }
        unsigned excl = x - v;
        pos[tid] = excl;
        offs[(size_t)bh * 65 + tid] = excl;
        if (tid == 63) offs[(size_t)bh * 65 + 64] = x;   // == S_
    }
    __syncthreads();
    unsigned int* op = order + (size_t)bh * S_;
    for (int s = tid; s < S_; s += 256) {
        unsigned g = idxp[s];
        unsigned p = atomicAdd(&pos[g], 1u);
        op[p] = (unsigned)s;
    }
}

// ---------------------------------------------------------------------------
// K5+K6 fused: aggv — per block: (bh, 2 groups x 2 parts). Phase A = old
// agg2 per (g,part) wave -> scaled part-sums to LDS (was a 19MB gpart HBM
// round-trip + a separate dispatch). Phase B = old gv arithmetic verbatim:
// part-0 waves add the two LDS rows float4-wise and dot with Wv rows.
// Summation order identical to the old agg2->gv pair (A*inv + B*inv, then
// per-c4 dot) -> gvn values bit-identical.
// ---------------------------------------------------------------------------
__global__ __launch_bounds__(256) void aggv_kernel(const unsigned short* __restrict__ khi,
                                                   const unsigned int* __restrict__ order,
                                                   const unsigned int* __restrict__ offs,
                                                   const float* __restrict__ Wv,
                                                   float* __restrict__ gvn) {
    __shared__ float lrows[4][C_];
    int tid = threadIdx.x;
    int w = tid >> 6, l = tid & 63;
    int h = blockIdx.y, b = blockIdx.z;
    int bh = b * H_ + h;
    int g = blockIdx.x * 2 + (w >> 1);   // 0..63
    int part = w & 1;
    unsigned beg = offs[(size_t)bh * 65 + g];
    unsigned end = offs[(size_t)bh * 65 + g + 1];
    int cnt = (int)(end - beg);
    float inv = 1.f / ((float)cnt + 1.f);
    const unsigned int* op = order + (size_t)bh * S_ + beg;
    const unsigned int* kbase = (const unsigned int*)(khi + (size_t)b * S_ * C_);
    float a0 = 0.f, a1 = 0.f, a2 = 0.f, a3 = 0.f, a4 = 0.f, a5 = 0.f;
    for (int base = part * 64; base < cnt; base += 128) {
        int m = cnt - base; if (m > 64) m = 64;
        unsigned sv = (l < m) ? op[base + l] : 0u;
        for (int i = 0; i < m; ++i) {
            int s = (int)__shfl((int)sv, i);
            const unsigned int* kp = kbase + (size_t)s * (C_ / 2) + l * 3;
            unsigned u0 = kp[0], u1 = kp[1], u2 = kp[2];
            a0 += bfu_lo(u0); a1 += bfu_hi(u0);
            a2 += bfu_lo(u1); a3 += bfu_hi(u1);
            a4 += bfu_lo(u2); a5 += bfu_hi(u2);
        }
    }
    float* lp = &lrows[w][l * 6];
    lp[0] = a0 * inv; lp[1] = a1 * inv; lp[2] = a2 * inv;
    lp[3] = a3 * inv; lp[4] = a4 * inv; lp[5] = a5 * inv;
    __syncthreads();
    if (part == 0) {
        // phase B == old gv: z = x + y per float4, then per-c4 dot with Wv row
        const float4* s0 = (const float4*)lrows[w];
        const float4* s1 = (const float4*)lrows[w + 1];
        const float* wrow = Wv + (size_t)(h * DH_ + l) * C_;
        float acc = 0.f;
#pragma unroll 8
        for (int c4 = 0; c4 < C_ / 4; ++c4) {
            float4 x = s0[c4];
            float4 y = s1[c4];
            float4 z = { x.x + y.x, x.y + y.y, x.z + y.z, x.w + y.w };
            float4 wv = *(const float4*)&wrow[c4 * 4];
            acc += z.x * wv.x + z.y * wv.y + z.z * wv.z + z.w * wv.w;
        }
        gvn[((size_t)bh * N_ + g) * DH_ + l] = acc;
    }
}

// ---------------------------------------------------------------------------
// K7: out — 4 tokens per block (was 1): Wp L2 stream amortized 4x
// (604 MB -> 151 MB), 4 FMA-chains per Wp load. Per-token loop order
// identical to prior rounds -> out bytes identical.
// ---------------------------------------------------------------------------
__global__ __launch_bounds__(384) void out_kernel(const float* __restrict__ gvn,
                                                  const float* __restrict__ Wp,
                                                  const float* __restrict__ bp,
                                                  float* __restrict__ out) {
    __shared__ float vals[4][C_];
    int blk = blockIdx.x;                 // 0..255
    int b = blk >> 4, n0 = (blk & 15) * 4;
    int t = threadIdx.x;
    int h = t >> 6, d = t & 63;
#pragma unroll
    for (int j = 0; j < 4; ++j)
        vals[j][t] = gvn[((size_t)(b * H_ + h) * N_ + n0 + j) * DH_ + d];
    __syncthreads();
    const float4* w4 = (const float4*)(Wp + (size_t)t * C_);
    float s0 = bp[t], s1 = s0, s2 = s0, s3 = s0;
    const float4* v0 = (const float4*)vals[0];
    const float4* v1 = (const float4*)vals[1];
    const float4* v2 = (const float4*)vals[2];
    const float4* v3 = (const float4*)vals[3];
#pragma unroll 4
    for (int i = 0; i < C_ / 4; ++i) {
        float4 w = w4[i];
        float4 a0 = v0[i]; s0 += a0.x * w.x + a0.y * w.y + a0.z * w.z + a0.w * w.w;
        float4 a1 = v1[i]; s1 += a1.x * w.x + a1.y * w.y + a1.z * w.z + a1.w * w.w;
        float4 a2 = v2[i]; s2 += a2.x * w.x + a2.y * w.y + a2.z * w.z + a2.w * w.w;
        float4 a3 = v3[i]; s3 += a3.x * w.x + a3.y * w.y + a3.z * w.z + a3.w * w.w;
    }
    size_t ob = ((size_t)b * N_ + n0) * C_ + t;
    out[ob] = s0;
    out[ob + C_] = s1;
    out[ob + 2 * C_] = s2;
    out[ob + 3 * C_] = s3;
}

// ---------------------------------------------------------------------------
extern "C" void kernel_launch(void* const* d_in, const int* in_sizes, int n_in,
                              void* d_out, int out_size, void* d_ws, size_t ws_size,
                              hipStream_t stream) {
    (void)in_sizes; (void)n_in; (void)out_size; (void)ws_size;
    const float* query = (const float*)d_in[0];
    const float* key   = (const float*)d_in[1];
    const float* Wq    = (const float*)d_in[2];
    const float* Wk    = (const float*)d_in[3];
    const float* Wv    = (const float*)d_in[4];
    const float* Wp    = (const float*)d_in[5];
    const float* bp    = (const float*)d_in[6];
    float* out = (float*)d_out;

    char* ws = (char*)d_ws;
    size_t off = 0;
    unsigned short* khi  = (unsigned short*)(ws + off); off += (size_t)B_ * S_ * C_ * 2;
    unsigned short* klo  = (unsigned short*)(ws + off); off += (size_t)B_ * S_ * C_ * 2;
    float* qk            = (float*)(ws + off);          off += (size_t)B_ * H_ * N_ * C_ * 4;
    unsigned short* qkhi = (unsigned short*)(ws + off); off += (size_t)B_ * H_ * N_ * C_ * 2;
    unsigned short* qklo = (unsigned short*)(ws + off); off += (size_t)B_ * H_ * N_ * C_ * 2;
    unsigned int* idx    = (unsigned int*)(ws + off);   off += (size_t)B_ * H_ * S_ * 4;
    unsigned int* order  = (unsigned int*)(ws + off);   off += (size_t)B_ * H_ * S_ * 4;
    unsigned int* offs   = (unsigned int*)(ws + off);   off += (size_t)B_ * H_ * 65 * 4;
    float* gvn           = (float*)(ws + off);          off += (size_t)B_ * H_ * N_ * DH_ * 4;
    unsigned int* fcnt   = (unsigned int*)(ws + off);   off += 256;
    unsigned int* flist  = (unsigned int*)(ws + off);   off += (size_t)LISTCAP * 4;

    hipMemsetAsync(fcnt, 0, 256, stream);

    prepqk_kernel<<<PREP_BLOCKS + QK_BLOCKS, 384, 0, stream>>>(key, khi, klo,
                                                               query, Wq, Wk, qk, qkhi, qklo);
    attn_kernel<<<dim3(S_ / 128, H_, B_), 256, 0, stream>>>(qkhi, qklo, khi, klo, idx, fcnt, flist);
    fixup_kernel<<<256, 256, 0, stream>>>(qk, key, flist, fcnt, idx);
    hist_build_kernel<<<B_ * H_, 256, 0, stream>>>(idx, offs, order);
    aggv_kernel<<<dim3(32, H_, B_), 256, 0, stream>>>(khi, order, offs, Wv, gvn);
    out_kernel<<<B_ * N_ / 4, 384, 0, stream>>>(gvn, Wp, bp, out);
}